// Round 8
// baseline (86.874 us; speedup 1.0000x reference)
//
#include <hip/hip_runtime.h>
#include <hip/hip_bf16.h>

// OnlineTripletLoss: B=8192, D=128, fp32 embeddings, int32 labels, scalar out.
// Symmetric upper-triangle tiling (half the Gram work); sq-norms folded INTO
// the MFMA via an extra K-slice (d2 = -2*acc, reduced monotonically in
// acc-space); raw s_barrier + counted vmcnt 3-buffer LDS pipeline;
// row&15 source-pre-swizzle; deterministic fixed-point finalize.

#define BB 8192
#define DD 128
#define MARGIN 0.2f
#define EPS 1e-12f

#define NBLK 32                        // 8192 / 256 tile-blocks per side
#define TILE 256                       // square tile: 8 waves x 32 rows
#define NTRI (NBLK * (NBLK + 1) / 2)   // 528 upper-triangle blocks
#define STAGE_COLS 64
#define NSTAGES 4                      // TILE / STAGE_COLS
#define STAGE_SHORTS (STAGE_COLS * DD) // 8192 shorts = 16 KB

typedef __attribute__((ext_vector_type(8))) short short8;
typedef __attribute__((ext_vector_type(16))) float f32x16;

__device__ inline unsigned short f2bf(float f) {
    __hip_bfloat16 h = __float2bfloat16(f);
    unsigned short u;
    __builtin_memcpy(&u, &h, 2);
    return u;
}

// ---- prep: bf16 copy + packed {sq,label} meta + init reduction state -------
__global__ __launch_bounds__(256) void prep_kernel(
    const float* __restrict__ x, const int* __restrict__ lab,
    unsigned short* __restrict__ xb, float2* __restrict__ meta,
    unsigned* __restrict__ hp2, unsigned* __restrict__ mn2,
    unsigned long long* __restrict__ fsum, unsigned* __restrict__ fdone) {
    int t = blockIdx.x * blockDim.x + threadIdx.x;   // 0 .. 8192*32-1
    int row = t >> 5;                                 // 32 threads per row
    const float4 v = reinterpret_cast<const float4*>(x)[t];

    union { unsigned short u[4]; uint2 w; } p;
    p.u[0] = f2bf(v.x); p.u[1] = f2bf(v.y);
    p.u[2] = f2bf(v.z); p.u[3] = f2bf(v.w);
    reinterpret_cast<uint2*>(xb)[t] = p.w;

    float s = v.x * v.x + v.y * v.y + v.z * v.z + v.w * v.w;
    #pragma unroll
    for (int m = 16; m >= 1; m >>= 1) s += __shfl_xor(s, m, 64);  // within 32-lane row group
    if ((t & 31) == 0) meta[row] = make_float2(s, __int_as_float(lab[row]));

    if (t < BB) { hp2[t] = 0u; mn2[t] = 0x7f800000u; }  // 0, +inf
    if (t == 0) { *fsum = 0ull; *fdone = 0u; }
}

// ---- main ------------------------------------------------------------------
// 528 blocks = upper-triangle (bi<=bj) of 32x32 tile-blocks, 512 thr = 8 waves.
// Each wave owns 32 rows of the bi-tile; cols of the bj-tile staged via
// global_load_lds in a 3-buffer pipeline with RAW barriers + counted vmcnt.
// d2(i,j) = -2*acc (norms inside MFMA) -> reduce min/max in acc-space.
// Row-side (hardest over j) accumulates in regs; col-side (hardest over i,
// the transpose contribution) reduces per group + atomics. Max/min idempotent
// -> diagonal-tile duplicates are harmless.
__global__ __launch_bounds__(512) void triplet_main(
    const unsigned short* __restrict__ xb, const float2* __restrict__ meta,
    unsigned* __restrict__ hp2, unsigned* __restrict__ mn2) {
    const int tid  = threadIdx.x;
    const int wave = tid >> 6;
    const int lane = tid & 63;
    const int l31  = lane & 31;
    const int lh1  = lane >> 5;

    // triangle decode: blockIdx.x -> (bi, bj), bi <= bj
    int bi = 0, rem = (int)blockIdx.x;
    while (rem >= NBLK - bi) { rem -= NBLK - bi; ++bi; }
    const int bj = bi + rem;
    const int rbase = bi * TILE + wave * 32;
    const int cbase = bj * TILE;

    __shared__ unsigned short sb[3][STAGE_SHORTS];   // 3 x 16 KB
    __shared__ float2 smeta[TILE];                   // 2 KB

    // A fragments: 32 rows, K=128 in 8 slices.
    // mfma_f32_32x32x16_bf16 A layout: row = lane&31, k = (lane>>5)*8 + i.
    short8 a[8];
    {
        const unsigned short* ar = xb + (size_t)(rbase + l31) * DD + lh1 * 8;
        #pragma unroll
        for (int s = 0; s < 8; ++s)
            a[s] = *reinterpret_cast<const short8*>(ar + s * 16);
    }
    // Extra K-slice folding the norms: A9 = [sqi, 1, 0...], B9 = [-0.5, -0.5*sqj, 0...]
    // => acc = dot - (sqi+sqj)/2, so d2 = -2*acc.
    short8 a9 = {0, 0, 0, 0, 0, 0, 0, 0};
    if (lh1 == 0) {
        a9[0] = (short)f2bf(meta[rbase + l31].x);
        a9[1] = (short)0x3F80;                       // 1.0 bf16
    }

    // C/D layout: col = lane&31, row_local = (r&3) + 8*(r>>2) + 4*(lane>>5).
    // Row labels packed 4/uint: li4[q] byte k = label of acc r = 4q+k.
    unsigned li4[4];
    #pragma unroll
    for (int q = 0; q < 4; ++q) {
        unsigned w = 0;
        #pragma unroll
        for (int k = 0; k < 4; ++k) {
            const int rl = 8 * q + 4 * lh1 + k;
            w |= ((unsigned)__float_as_int(meta[rbase + rl].y) & 255u) << (8 * k);
        }
        li4[q] = w;
    }
    // acc-space state: d2 = -2*acc is DECREASING in acc =>
    // hardest-positive (max d2 over eq)  = min acc over eq   (init +inf)
    // hardest-negative (min d2 over !eq) = max acc over !eq  (init -inf)
    float hpa[16], mna[16];
    #pragma unroll
    for (int r = 0; r < 16; ++r) { hpa[r] = __builtin_inff(); mna[r] = -__builtin_inff(); }

    if (tid < TILE) smeta[tid] = meta[cbase + tid];  // col {sq,label}

    // Stage 64 cols (16 KB): LDS dest linear, global SOURCE pre-swizzled so
    // LDS(row, b) = G(row, b ^ ((row&15)<<4)).
    auto stage = [&](int g, int buf) {
        const char* src_base = (const char*)(xb + (size_t)(cbase + g * STAGE_COLS) * DD);
        #pragma unroll
        for (int p = 0; p < 2; ++p) {
            const int o   = p * 8192 + tid * 16;            // linear byte offset
            const int row = o >> 8;
            const int byt = (o & 255) ^ ((row & 15) << 4);
            const char* src = src_base + row * 256 + byt;
            char* dst = (char*)&sb[buf][0] + p * 8192 + wave * 1024;
            __builtin_amdgcn_global_load_lds(
                (const __attribute__((address_space(1))) void*)src,
                (__attribute__((address_space(3))) void*)dst, 16, 0, 0);
        }
    };

    auto compute_group = [&](int st, int gg, int buf) {
        const char* base = (const char*)&sb[buf][0];
        const int jl = gg * 32 + l31;                       // col within stage tile
        const int rowoff = jl * 256;
        const int swz = (jl & 15) << 4;
        const float2 mj = smeta[st * STAGE_COLS + jl];
        const int lj = __float_as_int(mj.y) & 255;

        short8 b9 = {0, 0, 0, 0, 0, 0, 0, 0};
        if (lh1 == 0) {
            b9[0] = (short)0xBF00;                          // -0.5 bf16
            b9[1] = (short)f2bf(-0.5f * mj.x);
        }
        f32x16 acc = {};
        acc = __builtin_amdgcn_mfma_f32_32x32x16_bf16(a9, b9, acc, 0, 0, 0);
        short8 b[4];
        #pragma unroll
        for (int s = 0; s < 4; ++s)
            b[s] = *reinterpret_cast<const short8*>(
                base + rowoff + ((s * 32 + lh1 * 16) ^ swz));
        #pragma unroll
        for (int s = 0; s < 4; ++s)
            acc = __builtin_amdgcn_mfma_f32_32x32x16_bf16(a[s], b[s], acc, 0, 0, 0);
        #pragma unroll
        for (int s = 0; s < 4; ++s)
            b[s] = *reinterpret_cast<const short8*>(
                base + rowoff + (((s + 4) * 32 + lh1 * 16) ^ swz));
        #pragma unroll
        for (int s = 0; s < 4; ++s)
            acc = __builtin_amdgcn_mfma_f32_32x32x16_bf16(a[s + 4], b[s], acc, 0, 0, 0);

        // epilogue: shared selects feed BOTH row-side (persistent) and
        // col-side (transient, finalized per group). Self-pair (diag): acc~0
        // never beats true positives (acc ~ -d2/2 ~ -100) in the min.
        float hpc = __builtin_inff(), mnc = -__builtin_inff();
        #pragma unroll
        for (int q = 0; q < 4; ++q) {
            const unsigned lw = li4[q];
            #pragma unroll
            for (int k = 0; k < 4; ++k) {
                const int r = q * 4 + k;
                const bool eq = (int)((lw >> (8 * k)) & 255u) == lj;
                const float sp = eq ? acc[r] : __builtin_inff();
                const float sn = eq ? -__builtin_inff() : acc[r];
                hpa[r] = fminf(hpa[r], sp);
                mna[r] = fmaxf(mna[r], sn);
                hpc = fminf(hpc, sp);
                mnc = fmaxf(mnc, sn);
            }
        }
        // col-side: combine the two 32-row halves, then one atomic per col
        hpc = fminf(hpc, __shfl_xor(hpc, 32, 64));
        mnc = fmaxf(mnc, __shfl_xor(mnc, 32, 64));
        if (lh1 == 0) {
            const int j = cbase + st * STAGE_COLS + jl;
            atomicMax(&hp2[j], __float_as_uint(fmaxf(hpc * -2.0f, 0.0f)));
            atomicMin(&mn2[j], __float_as_uint(mnc * -2.0f));
        }
    };

    // ---- 3-buffer pipeline: RAW barrier + counted vmcnt (T3/T4) ------------
    // lgkmcnt(0) before the barrier: all this wave's ds_reads serviced before
    // anyone may overwrite that buffer after the barrier.
    stage(0, 0);
    stage(1, 1);
    #define PIPE_ITER(ST, PEND)                                                \
        asm volatile("s_waitcnt lgkmcnt(0) vmcnt(" #PEND ")" ::: "memory");    \
        __builtin_amdgcn_s_barrier();                                          \
        __builtin_amdgcn_sched_barrier(0);                                     \
        if ((ST) + 2 < NSTAGES) stage((ST) + 2, ((ST) + 2) % 3);               \
        compute_group((ST), 0, (ST) % 3);                                      \
        compute_group((ST), 1, (ST) % 3);
    PIPE_ITER(0, 2)
    PIPE_ITER(1, 2)
    PIPE_ITER(2, 2)
    PIPE_ITER(3, 0)
    #undef PIPE_ITER

    // row-side: reduce across the 32 column-lanes, then atomics (d2 = -2*acc)
    #pragma unroll
    for (int m = 1; m < 32; m <<= 1) {
        #pragma unroll
        for (int r = 0; r < 16; ++r) {
            hpa[r] = fminf(hpa[r], __shfl_xor(hpa[r], m, 64));
            mna[r] = fmaxf(mna[r], __shfl_xor(mna[r], m, 64));
        }
    }
    if (l31 == 0) {   // lanes 0 and 32 hold the two row-halves
        #pragma unroll
        for (int r = 0; r < 16; ++r) {
            const int i = rbase + (r & 3) + 8 * (r >> 2) + 4 * lh1;
            atomicMax(&hp2[i], __float_as_uint(fmaxf(hpa[r] * -2.0f, 0.0f)));
            atomicMin(&mn2[i], __float_as_uint(mna[r] * -2.0f));
        }
    }
}

// ---- finalize: per-row loss + deterministic fixed-point mean ---------------
// hardest_negative = min_neq d (every row has negatives: 64 labels / 8192).
__device__ inline float d_of(float d2) {
    return (d2 > EPS) ? sqrtf(d2) : 0.0f;
}

__global__ __launch_bounds__(1024) void finalize_kernel(
    const unsigned* __restrict__ hp2, const unsigned* __restrict__ mn2,
    unsigned long long* __restrict__ fsum, unsigned* __restrict__ fdone,
    float* __restrict__ out) {
    const int i = blockIdx.x * 1024 + threadIdx.x;   // 8 blocks x 1024 rows
    const float hpv = d_of(__uint_as_float(hp2[i]));
    const float mnv = d_of(__uint_as_float(mn2[i]));
    float acc = fmaxf(hpv - mnv + MARGIN, 0.0f);

    #pragma unroll
    for (int m = 1; m < 64; m <<= 1) acc += __shfl_xor(acc, m, 64);
    __shared__ float ws[16];
    const int wave = threadIdx.x >> 6;
    if ((threadIdx.x & 63) == 0) ws[wave] = acc;
    __syncthreads();
    if (threadIdx.x == 0) {
        float s = 0.0f;
        #pragma unroll
        for (int w = 0; w < 16; ++w) s += ws[w];
        // deterministic: integer atomic adds are order-independent
        atomicAdd(fsum, (unsigned long long)((double)s * 4294967296.0));
        __threadfence();
        const unsigned old = atomicAdd(fdone, 1u);
        if (old == gridDim.x - 1) {
            const unsigned long long total = atomicAdd(fsum, 0ull);
            out[0] = (float)((double)total / 4294967296.0 / (double)BB);
        }
    }
}

extern "C" void kernel_launch(void* const* d_in, const int* in_sizes, int n_in,
                              void* d_out, int out_size, void* d_ws, size_t ws_size,
                              hipStream_t stream) {
    const float* x = (const float*)d_in[0];
    const int* lab = (const int*)d_in[1];
    float* out = (float*)d_out;

    char* ws = (char*)d_ws;
    unsigned short* xb = (unsigned short*)ws;                          // 2 MB
    float2* meta = (float2*)(ws + (size_t)BB * DD * 2);                // 64 KB
    unsigned* hp2 = (unsigned*)(ws + (size_t)BB * DD * 2 + BB * 8);
    unsigned* mn2 = (unsigned*)(ws + (size_t)BB * DD * 2 + BB * 12);
    unsigned long long* fsum = (unsigned long long*)(ws + (size_t)BB * DD * 2 + BB * 16);
    unsigned* fdone = (unsigned*)(ws + (size_t)BB * DD * 2 + BB * 16 + 8);

    prep_kernel<<<(BB * DD / 4) / 256, 256, 0, stream>>>(x, lab, xb, meta, hp2, mn2, fsum, fdone);
    triplet_main<<<NTRI, 512, 0, stream>>>(xb, meta, hp2, mn2);
    finalize_kernel<<<BB / 1024, 1024, 0, stream>>>(hp2, mn2, fsum, fdone, out);
}

// Round 9
// 49.853 us; speedup vs baseline: 1.7426x; 1.7426x over previous
//
#include <hip/hip_runtime.h>
#include <hip/hip_bf16.h>

// OnlineTripletLoss: B=8192, D=128, fp32 embeddings, int32 labels, scalar out.
// d2-space fused reductions; 32x32x16 bf16 MFMA; 3-buffer LDS pipeline with
// RAW s_barrier + counted vmcnt (round 7 used __syncthreads -> full vmcnt(0)
// drain each stage = the stall); row&15 source-pre-swizzle; deferred-sqi
// epilogue; deterministic fixed-point finalize.
// Round-8 lesson: triangle+col-side+norm-fold blew regs to 128 and spilled
// 74 MB scratch -- reverted; this round changes ONLY the barrier form.

#define BB 8192
#define DD 128
#define MARGIN 0.2f
#define EPS 1e-12f

#define COLS_PER_BLOCK 512
#define ROWS_PER_BLOCK 256                     // 8 waves x 32 rows
#define STAGE_COLS 64
#define NSTAGES 8                              // COLS_PER_BLOCK / STAGE_COLS
#define STAGE_SHORTS (STAGE_COLS * DD)         // 8192 shorts = 16 KB

typedef __attribute__((ext_vector_type(8))) short short8;
typedef __attribute__((ext_vector_type(16))) float f32x16;

__device__ inline unsigned short f2bf(float f) {
    __hip_bfloat16 h = __float2bfloat16(f);
    unsigned short u;
    __builtin_memcpy(&u, &h, 2);
    return u;
}

// ---- prep: bf16 copy + packed {sq,label} meta + init reduction state -------
__global__ __launch_bounds__(256) void prep_kernel(
    const float* __restrict__ x, const int* __restrict__ lab,
    unsigned short* __restrict__ xb, float2* __restrict__ meta,
    unsigned* __restrict__ hp2, unsigned* __restrict__ mn2,
    unsigned long long* __restrict__ fsum, unsigned* __restrict__ fdone) {
    int t = blockIdx.x * blockDim.x + threadIdx.x;   // 0 .. 8192*32-1
    int row = t >> 5;                                 // 32 threads per row
    const float4 v = reinterpret_cast<const float4*>(x)[t];

    union { unsigned short u[4]; uint2 w; } p;
    p.u[0] = f2bf(v.x); p.u[1] = f2bf(v.y);
    p.u[2] = f2bf(v.z); p.u[3] = f2bf(v.w);
    reinterpret_cast<uint2*>(xb)[t] = p.w;

    float s = v.x * v.x + v.y * v.y + v.z * v.z + v.w * v.w;
    #pragma unroll
    for (int m = 16; m >= 1; m >>= 1) s += __shfl_xor(s, m, 64);  // within 32-lane row group
    if ((t & 31) == 0) meta[row] = make_float2(s, __int_as_float(lab[row]));

    if (t < BB) { hp2[t] = 0u; mn2[t] = 0x7f800000u; }  // 0, +inf
    if (t == 0) { *fsum = 0ull; *fdone = 0u; }
}

// ---- main ------------------------------------------------------------------
// grid (32, 16), 512 threads = 8 waves x 32 rows = 256 rows x 512-col chunk.
// B tiles of 64 cols in a 3-buffer LDS pipeline; counted vmcnt keeps 2 stages
// in flight ACROSS raw barriers; compute never waits on a fresh load.
__global__ __launch_bounds__(512) void triplet_main(
    const unsigned short* __restrict__ xb, const float2* __restrict__ meta,
    unsigned* __restrict__ hp2, unsigned* __restrict__ mn2) {
    const int tid  = threadIdx.x;
    const int wave = tid >> 6;
    const int lane = tid & 63;
    const int l31  = lane & 31;
    const int lh1  = lane >> 5;
    const int rbase = blockIdx.x * ROWS_PER_BLOCK + wave * 32;
    const int cbase = blockIdx.y * COLS_PER_BLOCK;

    __shared__ unsigned short sb[3][STAGE_SHORTS];   // 3 x 16 KB
    __shared__ float2 smeta[COLS_PER_BLOCK];         // 4 KB

    // A fragments: 32 rows, K=128 in 8 slices (held whole kernel).
    // mfma_f32_32x32x16_bf16 A layout: row = lane&31, k = (lane>>5)*8 + i.
    short8 a[8];
    {
        const unsigned short* ar = xb + (size_t)(rbase + l31) * DD + lh1 * 8;
        #pragma unroll
        for (int s = 0; s < 8; ++s)
            a[s] = *reinterpret_cast<const short8*>(ar + s * 16);
    }

    // C/D layout: col = lane&31, row_local = (r&3) + 8*(r>>2) + 4*(lane>>5).
    // Row labels packed 4/uint (labels < 64): li4[q] byte k = label of acc r=4q+k.
    unsigned li4[4];
    float hp[16], mn[16];
    #pragma unroll
    for (int q = 0; q < 4; ++q) {
        unsigned w = 0;
        #pragma unroll
        for (int k = 0; k < 4; ++k) {
            const int rl = 8 * q + 4 * lh1 + k;
            w |= ((unsigned)__float_as_int(meta[rbase + rl].y) & 255u) << (8 * k);
        }
        li4[q] = w;
    }
    #pragma unroll
    for (int r = 0; r < 16; ++r) { hp[r] = -__builtin_inff(); mn[r] = __builtin_inff(); }

    smeta[tid] = meta[cbase + tid];   // 512 cols of {sq,label} -> LDS

    // Stage 64 cols (16 KB) into sb[buf]: 2 x 16B gload_lds per thread.
    // LDS dest linear (wave-uniform base + lane*16); global SOURCE pre-swizzled:
    // LDS(row, b) = G(row, b ^ ((row&15)<<4)).
    auto stage = [&](int g, int buf) {
        const char* src_base = (const char*)(xb + (size_t)(cbase + g * STAGE_COLS) * DD);
        #pragma unroll
        for (int p = 0; p < 2; ++p) {
            const int o   = p * 8192 + tid * 16;            // linear byte offset
            const int row = o >> 8;
            const int byt = (o & 255) ^ ((row & 15) << 4);
            const char* src = src_base + row * 256 + byt;
            char* dst = (char*)&sb[buf][0] + p * 8192 + wave * 1024;
            __builtin_amdgcn_global_load_lds(
                (const __attribute__((address_space(1))) void*)src,
                (__attribute__((address_space(3))) void*)dst, 16, 0, 0);
        }
    };

    auto compute_group = [&](int st, int gg, int buf) {
        const char* base = (const char*)&sb[buf][0];
        const int jl = gg * 32 + l31;                       // col within stage
        const int rowoff = jl * 256;
        const int swz = (jl & 15) << 4;
        f32x16 acc = {};
        short8 b[4];
        #pragma unroll
        for (int s = 0; s < 4; ++s)
            b[s] = *reinterpret_cast<const short8*>(
                base + rowoff + ((s * 32 + lh1 * 16) ^ swz));
        #pragma unroll
        for (int s = 0; s < 4; ++s)
            acc = __builtin_amdgcn_mfma_f32_32x32x16_bf16(a[s], b[s], acc, 0, 0, 0);
        #pragma unroll
        for (int s = 0; s < 4; ++s)
            b[s] = *reinterpret_cast<const short8*>(
                base + rowoff + (((s + 4) * 32 + lh1 * 16) ^ swz));
        #pragma unroll
        for (int s = 0; s < 4; ++s)
            acc = __builtin_amdgcn_mfma_f32_32x32x16_bf16(a[s + 4], b[s], acc, 0, 0, 0);

        const float2 mj = smeta[st * STAGE_COLS + jl];
        const float sqj = mj.x;
        const int   lj  = __float_as_int(mj.y);
        #pragma unroll
        for (int q = 0; q < 4; ++q) {
            const unsigned lw = li4[q];
            #pragma unroll
            for (int k = 0; k < 4; ++k) {
                const int r = q * 4 + k;
                const float d2p = fmaf(acc[r], -2.0f, sqj);  // sqj - 2*dot (sqi deferred)
                const bool eq = (int)((lw >> (8 * k)) & 255u) == lj;
                // self-pair folds into hp: its d2' ~ -sqi -> final ~0, never wins.
                hp[r] = fmaxf(hp[r], eq ? d2p : -__builtin_inff());
                mn[r] = fminf(mn[r], eq ? __builtin_inff() : d2p);
            }
        }
    };

    // ---- 3-buffer pipeline: RAW barrier + counted vmcnt --------------------
    // At iter ST: lgkmcnt(0) (my reads of buf (ST+2)%3 from iter ST-1 done;
    // smeta writes done) + vmcnt(2) (stage ST's loads landed; ST+1 in flight),
    // barrier, sched_barrier(0) (no ds_read hoisting above), issue stage ST+2,
    // compute ST. __syncthreads() would force vmcnt(0): the round-7 stall.
    stage(0, 0);
    stage(1, 1);
    #define PIPE_ITER(ST, PEND)                                                \
        asm volatile("s_waitcnt lgkmcnt(0) vmcnt(" #PEND ")" ::: "memory");    \
        __builtin_amdgcn_s_barrier();                                          \
        __builtin_amdgcn_sched_barrier(0);                                     \
        if ((ST) + 2 < NSTAGES) stage((ST) + 2, ((ST) + 2) % 3);               \
        compute_group((ST), 0, (ST) % 3);                                      \
        compute_group((ST), 1, (ST) % 3);
    PIPE_ITER(0, 2)
    PIPE_ITER(1, 2)
    PIPE_ITER(2, 2)
    PIPE_ITER(3, 2)
    PIPE_ITER(4, 2)
    PIPE_ITER(5, 2)
    PIPE_ITER(6, 2)
    PIPE_ITER(7, 0)
    #undef PIPE_ITER

    // add deferred sqi; clamp hp to >=0 (exact: reference max(d*posmask) >= 0)
    #pragma unroll
    for (int r = 0; r < 16; ++r) {
        const int rl = (r & 3) + 8 * (r >> 2) + 4 * lh1;
        const float sqi = meta[rbase + rl].x;
        hp[r] = fmaxf(sqi + hp[r], 0.0f);   // -inf (no positive seen) -> 0
        mn[r] = sqi + mn[r];                // +inf stays +inf
    }
    // reduce across the 32 column-lanes (xor<32 stays within each half-wave)
    #pragma unroll
    for (int m = 1; m < 32; m <<= 1) {
        #pragma unroll
        for (int r = 0; r < 16; ++r) {
            hp[r] = fmaxf(hp[r], __shfl_xor(hp[r], m, 64));
            mn[r] = fminf(mn[r], __shfl_xor(mn[r], m, 64));
        }
    }
    if (l31 == 0) {   // lanes 0 and 32 hold the two row-halves
        #pragma unroll
        for (int r = 0; r < 16; ++r) {
            const int i = rbase + (r & 3) + 8 * (r >> 2) + 4 * lh1;
            atomicMax(&hp2[i], __float_as_uint(hp[r]));  // >=0: uint order == float order
            atomicMin(&mn2[i], __float_as_uint(mn[r]));  // >=0 or +inf
        }
    }
}

// ---- finalize: per-row loss + deterministic fixed-point mean ---------------
// hardest_negative = min_neq d (every row has negatives: 64 labels / 8192).
__device__ inline float d_of(float d2) {
    return (d2 > EPS) ? sqrtf(d2) : 0.0f;
}

__global__ __launch_bounds__(1024) void finalize_kernel(
    const unsigned* __restrict__ hp2, const unsigned* __restrict__ mn2,
    unsigned long long* __restrict__ fsum, unsigned* __restrict__ fdone,
    float* __restrict__ out) {
    const int i = blockIdx.x * 1024 + threadIdx.x;   // 8 blocks x 1024 rows
    const float hpv = d_of(__uint_as_float(hp2[i]));
    const float mnv = d_of(__uint_as_float(mn2[i]));
    float acc = fmaxf(hpv - mnv + MARGIN, 0.0f);

    #pragma unroll
    for (int m = 1; m < 64; m <<= 1) acc += __shfl_xor(acc, m, 64);
    __shared__ float ws[16];
    const int wave = threadIdx.x >> 6;
    if ((threadIdx.x & 63) == 0) ws[wave] = acc;
    __syncthreads();
    if (threadIdx.x == 0) {
        float s = 0.0f;
        #pragma unroll
        for (int w = 0; w < 16; ++w) s += ws[w];
        // deterministic: integer atomic adds are order-independent
        atomicAdd(fsum, (unsigned long long)((double)s * 4294967296.0));
        __threadfence();
        const unsigned old = atomicAdd(fdone, 1u);
        if (old == gridDim.x - 1) {
            const unsigned long long total = atomicAdd(fsum, 0ull);
            out[0] = (float)((double)total / 4294967296.0 / (double)BB);
        }
    }
}

extern "C" void kernel_launch(void* const* d_in, const int* in_sizes, int n_in,
                              void* d_out, int out_size, void* d_ws, size_t ws_size,
                              hipStream_t stream) {
    const float* x = (const float*)d_in[0];
    const int* lab = (const int*)d_in[1];
    float* out = (float*)d_out;

    char* ws = (char*)d_ws;
    unsigned short* xb = (unsigned short*)ws;                          // 2 MB
    float2* meta = (float2*)(ws + (size_t)BB * DD * 2);                // 64 KB
    unsigned* hp2 = (unsigned*)(ws + (size_t)BB * DD * 2 + BB * 8);
    unsigned* mn2 = (unsigned*)(ws + (size_t)BB * DD * 2 + BB * 12);
    unsigned long long* fsum = (unsigned long long*)(ws + (size_t)BB * DD * 2 + BB * 16);
    unsigned* fdone = (unsigned*)(ws + (size_t)BB * DD * 2 + BB * 16 + 8);

    prep_kernel<<<(BB * DD / 4) / 256, 256, 0, stream>>>(x, lab, xb, meta, hp2, mn2, fsum, fdone);
    dim3 grid(BB / ROWS_PER_BLOCK, BB / COLS_PER_BLOCK);
    triplet_main<<<grid, 512, 0, stream>>>(xb, meta, hp2, mn2);
    finalize_kernel<<<BB / 1024, 1024, 0, stream>>>(hp2, mn2, fsum, fdone, out);
}

// Round 10
// 40.161 us; speedup vs baseline: 2.1631x; 1.2413x over previous
//
#include <hip/hip_runtime.h>
#include <hip/hip_bf16.h>

// OnlineTripletLoss: B=8192, D=128, fp32 embeddings, int32 labels, scalar out.
// Occupancy-first rebuild: 16x16x32 bf16 MFMA (VGPR-lean, target <=64 regs ->
// 8 waves/SIMD, 32 waves/CU; every 32x32 variant sat at 88+ regs = 16 waves/CU
// = 43us plateau). 3-buffer LDS pipeline, counted vmcnt, raw s_barrier;
// row&15 source-pre-swizzle; sqi-deferred epilogue; packed labels;
// deterministic fixed-point finalize.

#define BB 8192
#define DD 128
#define MARGIN 0.2f
#define EPS 1e-12f

#define COLS_PER_BLOCK 512
#define ROWS_PER_BLOCK 128                     // 8 waves x 16 rows
#define STAGE_COLS 32
#define NSTAGES 16                             // COLS_PER_BLOCK / STAGE_COLS
#define STAGE_SHORTS (STAGE_COLS * DD)         // 4096 shorts = 8 KB

typedef __attribute__((ext_vector_type(8))) short short8;
typedef __attribute__((ext_vector_type(4))) float f32x4;

__device__ inline unsigned short f2bf(float f) {
    __hip_bfloat16 h = __float2bfloat16(f);
    unsigned short u;
    __builtin_memcpy(&u, &h, 2);
    return u;
}

// ---- prep: bf16 copy + packed {sq,label} meta + init reduction state -------
__global__ __launch_bounds__(256) void prep_kernel(
    const float* __restrict__ x, const int* __restrict__ lab,
    unsigned short* __restrict__ xb, float2* __restrict__ meta,
    unsigned* __restrict__ hp2, unsigned* __restrict__ mn2,
    unsigned long long* __restrict__ fsum, unsigned* __restrict__ fdone) {
    int t = blockIdx.x * blockDim.x + threadIdx.x;   // 0 .. 8192*32-1
    int row = t >> 5;                                 // 32 threads per row
    const float4 v = reinterpret_cast<const float4*>(x)[t];

    union { unsigned short u[4]; uint2 w; } p;
    p.u[0] = f2bf(v.x); p.u[1] = f2bf(v.y);
    p.u[2] = f2bf(v.z); p.u[3] = f2bf(v.w);
    reinterpret_cast<uint2*>(xb)[t] = p.w;

    float s = v.x * v.x + v.y * v.y + v.z * v.z + v.w * v.w;
    #pragma unroll
    for (int m = 16; m >= 1; m >>= 1) s += __shfl_xor(s, m, 64);  // within 32-lane row group
    if ((t & 31) == 0) meta[row] = make_float2(s, __int_as_float(lab[row]));

    if (t < BB) { hp2[t] = 0u; mn2[t] = 0x7f800000u; }  // 0, +inf
    if (t == 0) { *fsum = 0ull; *fdone = 0u; }
}

// ---- main ------------------------------------------------------------------
// grid (64, 16), 512 threads = 8 waves x 16 rows = 128 rows x 512-col chunk.
// 1024 blocks = 4/CU; LDS 28 KB, VGPR-lean -> 32 waves/CU (the lever: all
// 16-wave/CU variants plateaued at 43us with every pipe <30% busy).
// 32-col B tiles in a 3-buffer LDS pipeline; counted vmcnt keeps the next
// stage's load in flight across raw barriers.
__global__ __launch_bounds__(512) void triplet_main(
    const unsigned short* __restrict__ xb, const float2* __restrict__ meta,
    unsigned* __restrict__ hp2, unsigned* __restrict__ mn2) {
    const int tid  = threadIdx.x;
    const int wave = tid >> 6;
    const int lane = tid & 63;
    const int l15  = lane & 15;
    const int lhi  = lane >> 4;
    const int rbase = blockIdx.x * ROWS_PER_BLOCK + wave * 16;
    const int cbase = blockIdx.y * COLS_PER_BLOCK;

    __shared__ unsigned short sb[3][STAGE_SHORTS];   // 3 x 8 KB
    __shared__ float2 smeta[COLS_PER_BLOCK];         // 4 KB

    // A fragments: 16 rows, K=128 in 4 slices (held whole kernel).
    // mfma_f32_16x16x32_bf16 A layout: row = lane&15, k = (lane>>4)*8 + i.
    short8 a[4];
    {
        const unsigned short* ar = xb + (size_t)(rbase + l15) * DD + lhi * 8;
        #pragma unroll
        for (int s = 0; s < 4; ++s)
            a[s] = *reinterpret_cast<const short8*>(ar + s * 32);
    }

    // C/D layout: col = lane&15, row_local = (lane>>4)*4 + r.
    // Row labels packed 4/uint (labels < 64): byte r = label of row lhi*4+r.
    unsigned liw = 0;
    {
        #pragma unroll
        for (int k = 0; k < 4; ++k)
            liw |= ((unsigned)__float_as_int(meta[rbase + lhi * 4 + k].y) & 255u) << (8 * k);
    }
    float hp[4], mn[4];
    #pragma unroll
    for (int r = 0; r < 4; ++r) { hp[r] = -__builtin_inff(); mn[r] = __builtin_inff(); }

    smeta[tid] = meta[cbase + tid];   // 512 cols of {sq,label} -> LDS

    // Stage 32 cols (8 KB) into sb[buf]: 1 x 16B gload_lds per thread.
    // LDS dest linear (wave-uniform base + lane*16); global SOURCE pre-swizzled:
    // LDS(row, b) = G(row, b ^ ((row&15)<<4)).
    auto stage = [&](int g, int buf) {
        const char* src_base = (const char*)(xb + (size_t)(cbase + g * STAGE_COLS) * DD);
        const int o   = tid * 16;                       // 0..8191
        const int row = o >> 8;                         // 0..31
        const int byt = (o & 255) ^ ((row & 15) << 4);
        const char* src = src_base + row * 256 + byt;
        char* dst = (char*)&sb[buf][0] + wave * 1024;
        __builtin_amdgcn_global_load_lds(
            (const __attribute__((address_space(1))) void*)src,
            (__attribute__((address_space(3))) void*)dst, 16, 0, 0);
    };

    auto compute_group = [&](int st, int gg, const char* base) {
        const int jl = gg * 16 + l15;                   // col within stage (0..31)
        const int rowoff = jl * 256;
        const int swz = (jl & 15) << 4;
        short8 b[4];
        #pragma unroll
        for (int s = 0; s < 4; ++s)
            b[s] = *reinterpret_cast<const short8*>(
                base + rowoff + ((s * 64 + lhi * 16) ^ swz));
        f32x4 acc = {};
        #pragma unroll
        for (int s = 0; s < 4; ++s)
            acc = __builtin_amdgcn_mfma_f32_16x16x32_bf16(a[s], b[s], acc, 0, 0, 0);

        const float2 mj = smeta[st * STAGE_COLS + jl];
        const float sqj = mj.x;
        const int   lj  = __float_as_int(mj.y) & 255;
        #pragma unroll
        for (int r = 0; r < 4; ++r) {
            const float d2p = fmaf(acc[r], -2.0f, sqj);  // sqj - 2*dot (sqi deferred)
            const bool eq = (int)((liw >> (8 * r)) & 255u) == lj;
            // self-pair folds into hp: its d2' ~ -sqi -> final ~0, never wins.
            hp[r] = fmaxf(hp[r], eq ? d2p : -__builtin_inff());
            mn[r] = fminf(mn[r], eq ? __builtin_inff() : d2p);
        }
    };

    // ---- 3-buffer pipeline: RAW barrier + counted vmcnt --------------------
    // At iter ST: lgkmcnt(0) (my reads of the buffer stage ST+2 will overwrite
    // finished; smeta write done) + vmcnt(1) (stage ST's load landed, ST+1's
    // still in flight), barrier, no-hoist fence, issue stage ST+2, compute ST.
    stage(0, 0);
    stage(1, 1);
    #pragma unroll
    for (int st = 0; st < NSTAGES; ++st) {
        if (st < NSTAGES - 1)
            asm volatile("s_waitcnt lgkmcnt(0) vmcnt(1)" ::: "memory");
        else
            asm volatile("s_waitcnt lgkmcnt(0) vmcnt(0)" ::: "memory");
        __builtin_amdgcn_s_barrier();
        __builtin_amdgcn_sched_barrier(0);
        if (st + 2 < NSTAGES) stage(st + 2, (st + 2) % 3);
        const char* base = (const char*)&sb[st % 3][0];
        compute_group(st, 0, base);
        __builtin_amdgcn_sched_barrier(0);   // keep live sets (and VGPRs) small
        compute_group(st, 1, base);
    }

    // add deferred sqi; clamp hp to >=0 (exact: reference max(d*posmask) >= 0)
    #pragma unroll
    for (int r = 0; r < 4; ++r) {
        const float sqi = meta[rbase + lhi * 4 + r].x;
        hp[r] = fmaxf(sqi + hp[r], 0.0f);   // -inf (no positive seen) -> 0
        mn[r] = sqi + mn[r];                // +inf stays +inf
    }
    // reduce across the 16 column-lanes (same lhi group shares rows)
    #pragma unroll
    for (int m = 1; m < 16; m <<= 1) {
        #pragma unroll
        for (int r = 0; r < 4; ++r) {
            hp[r] = fmaxf(hp[r], __shfl_xor(hp[r], m, 64));
            mn[r] = fminf(mn[r], __shfl_xor(mn[r], m, 64));
        }
    }
    if (l15 == 0) {   // lanes 0,16,32,48 hold the four 4-row groups
        #pragma unroll
        for (int r = 0; r < 4; ++r) {
            const int i = rbase + lhi * 4 + r;
            atomicMax(&hp2[i], __float_as_uint(hp[r]));  // >=0: uint order == float order
            atomicMin(&mn2[i], __float_as_uint(mn[r]));  // >=0 or +inf
        }
    }
}

// ---- finalize: per-row loss + deterministic fixed-point mean ---------------
// hardest_negative = min_neq d (every row has negatives: 64 labels / 8192).
__device__ inline float d_of(float d2) {
    return (d2 > EPS) ? sqrtf(d2) : 0.0f;
}

__global__ __launch_bounds__(1024) void finalize_kernel(
    const unsigned* __restrict__ hp2, const unsigned* __restrict__ mn2,
    unsigned long long* __restrict__ fsum, unsigned* __restrict__ fdone,
    float* __restrict__ out) {
    const int i = blockIdx.x * 1024 + threadIdx.x;   // 8 blocks x 1024 rows
    const float hpv = d_of(__uint_as_float(hp2[i]));
    const float mnv = d_of(__uint_as_float(mn2[i]));
    float acc = fmaxf(hpv - mnv + MARGIN, 0.0f);

    #pragma unroll
    for (int m = 1; m < 64; m <<= 1) acc += __shfl_xor(acc, m, 64);
    __shared__ float ws[16];
    const int wave = threadIdx.x >> 6;
    if ((threadIdx.x & 63) == 0) ws[wave] = acc;
    __syncthreads();
    if (threadIdx.x == 0) {
        float s = 0.0f;
        #pragma unroll
        for (int w = 0; w < 16; ++w) s += ws[w];
        // deterministic: integer atomic adds are order-independent
        atomicAdd(fsum, (unsigned long long)((double)s * 4294967296.0));
        __threadfence();
        const unsigned old = atomicAdd(fdone, 1u);
        if (old == gridDim.x - 1) {
            const unsigned long long total = atomicAdd(fsum, 0ull);
            out[0] = (float)((double)total / 4294967296.0 / (double)BB);
        }
    }
}

extern "C" void kernel_launch(void* const* d_in, const int* in_sizes, int n_in,
                              void* d_out, int out_size, void* d_ws, size_t ws_size,
                              hipStream_t stream) {
    const float* x = (const float*)d_in[0];
    const int* lab = (const int*)d_in[1];
    float* out = (float*)d_out;

    char* ws = (char*)d_ws;
    unsigned short* xb = (unsigned short*)ws;                          // 2 MB
    float2* meta = (float2*)(ws + (size_t)BB * DD * 2);                // 64 KB
    unsigned* hp2 = (unsigned*)(ws + (size_t)BB * DD * 2 + BB * 8);
    unsigned* mn2 = (unsigned*)(ws + (size_t)BB * DD * 2 + BB * 12);
    unsigned long long* fsum = (unsigned long long*)(ws + (size_t)BB * DD * 2 + BB * 16);
    unsigned* fdone = (unsigned*)(ws + (size_t)BB * DD * 2 + BB * 16 + 8);

    prep_kernel<<<(BB * DD / 4) / 256, 256, 0, stream>>>(x, lab, xb, meta, hp2, mn2, fsum, fdone);
    dim3 grid(BB / ROWS_PER_BLOCK, BB / COLS_PER_BLOCK);
    triplet_main<<<grid, 512, 0, stream>>>(xb, meta, hp2, mn2);
    finalize_kernel<<<BB / 1024, 1024, 0, stream>>>(hp2, mn2, fsum, fdone, out);
}